// Round 10
// baseline (203.859 us; speedup 1.0000x reference)
//
#include <hip/hip_runtime.h>
#include <math.h>

#define BATCH 2
#define TSEQ 4096
#define DM 768
#define HEADS 4
#define DHEAD 64
#define DIMQ 256                  // HEADS*DHEAD
#define MROWS (BATCH*TSEQ)        // 8192
#define CHUNK 64
#define NCHUNK (TSEQ/CHUNK)       // 64
#define NBH (BATCH*HEADS)         // 8
#define STATE (DHEAD*DHEAD + DHEAD)  // 4160
#define KSPLIT (DM*2)             // 1536 stored k-cols for x/wt: [hi 768 | lo 768]
#define KS2 (DIMQ*2)              // 512 stored k-cols for attn/wot: [hi 256 | lo 256]
#define STR 72                    // LDS bf16 row stride: 144B (16B-aligned, bank-stride 4)

typedef __attribute__((ext_vector_type(8))) short bf16x8;
typedef __attribute__((ext_vector_type(4))) float f32x4;

__device__ __forceinline__ float act_elu1(float x){ return x > 0.f ? x + 1.f : expf(x); }
__device__ __forceinline__ float act_sig(float x){ return 1.f/(1.f + expf(-x)); }

__device__ __forceinline__ void fma4(float4& o, float a, const float4& b){
    o.x = fmaf(a, b.x, o.x); o.y = fmaf(a, b.y, o.y);
    o.z = fmaf(a, b.z, o.z); o.w = fmaf(a, b.w, o.w);
}

// round-to-nearest-even fp32 -> bf16
__device__ __forceinline__ unsigned short bf16_rne(float f){
    unsigned u = __float_as_uint(f);
    u += 0x7FFFu + ((u >> 16) & 1u);
    return (unsigned short)(u >> 16);
}
__device__ __forceinline__ float bf2f(unsigned short h){
    return __uint_as_float(((unsigned)h) << 16);
}

// NOTE: LDS dest is wave-uniform base + lane*16B (m104/m108).
__device__ __forceinline__ void gload_lds16(const void* g, void* l){
    __builtin_amdgcn_global_load_lds(
        (const __attribute__((address_space(1))) unsigned char*)g,
        (__attribute__((address_space(3))) unsigned char*)l, 16, 0, 0);
}

// split 16 consecutive floats into bf16 hi/lo
__device__ __forceinline__ void split16(const float* __restrict__ src,
                                        unsigned short* h, unsigned short* l){
    #pragma unroll
    for (int j4 = 0; j4 < 4; j4++){
        float4 v = *(const float4*)(src + j4*4);
        float vv[4] = {v.x, v.y, v.z, v.w};
        #pragma unroll
        for (int j = 0; j < 4; j++){
            h[j4*4+j] = bf16_rne(vv[j]);
            float hf = bf2f(h[j4*4+j]);
            l[j4*4+j] = bf16_rne(vv[j] - hf);
        }
    }
}

// ---------------------------------------------------------------------------
// Kernel 0: merged prep (coalesced x-split). (r9)
// ---------------------------------------------------------------------------
__global__ __launch_bounds__(256)
void prep(const float* __restrict__ x,
          const float* __restrict__ Wq, const float* __restrict__ Wk,
          const float* __restrict__ Wv, const float* __restrict__ Wg,
          unsigned short* __restrict__ xs, unsigned short* __restrict__ wt)
{
    __shared__ float T[64][65];
    const int bid = blockIdx.x;
    const int t = threadIdx.x;

    if (bid < MROWS) {                       // ---- x split ----
        if (t < 192) {
            const int r = bid;
            const int c = t * 4;
            float4 v = *(const float4*)&x[(size_t)r*DM + c];
            float vv[4] = {v.x, v.y, v.z, v.w};
            unsigned short h[4], l[4];
            #pragma unroll
            for (int j = 0; j < 4; j++){
                h[j] = bf16_rne(vv[j]);
                float hf = bf2f(h[j]);
                l[j] = bf16_rne(vv[j] - hf);
            }
            ushort4 h4 = {h[0],h[1],h[2],h[3]}, l4 = {l[0],l[1],l[2],l[3]};
            *(ushort4*)&xs[(size_t)r*KSPLIT + c] = h4;
            *(ushort4*)&xs[(size_t)r*KSPLIT + DM + c] = l4;
        }
        return;
    }

    const int i = bid - MROWS;
    const int n0 = (i % 24)*64, k0 = (i / 24)*64;
    const float* W; int ldw, c0;
    if      (n0 < 256) { W = Wq; ldw = DIMQ; c0 = n0;       }
    else if (n0 < 512) { W = Wk; ldw = DIMQ; c0 = n0 - 256; }
    else if (n0 < 768) { W = Wv; ldw = DIMQ; c0 = n0 - 512; }
    else               { W = Wg; ldw = DM;   c0 = n0 - 768; }

    const int lr = t >> 4, lc = (t & 15) * 4;
    #pragma unroll
    for (int ii = 0; ii < 4; ii++){
        int r = lr + ii*16;
        float4 v = *(const float4*)&W[(size_t)(k0+r)*ldw + c0 + lc];
        T[r][lc+0]=v.x; T[r][lc+1]=v.y; T[r][lc+2]=v.z; T[r][lc+3]=v.w;
    }
    __syncthreads();
    const int rn = t >> 2, kc = (t & 3) * 16;
    unsigned short hb[16], lb[16];
    #pragma unroll
    for (int j = 0; j < 16; j++){
        float f = T[kc+j][rn];
        hb[j] = bf16_rne(f);
        float hf = bf2f(hb[j]);
        lb[j] = bf16_rne(f - hf);
    }
    size_t base = (size_t)(n0+rn)*KSPLIT + k0 + kc;
    #pragma unroll
    for (int q = 0; q < 4; q++){
        ushort4 hv = {hb[q*4],hb[q*4+1],hb[q*4+2],hb[q*4+3]};
        ushort4 lv = {lb[q*4],lb[q*4+1],lb[q*4+2],lb[q*4+3]};
        *(ushort4*)&wt[base + q*4] = hv;
        *(ushort4*)&wt[base + DM + q*4] = lv;
    }
}

// ---------------------------------------------------------------------------
// Kernel 1: fused projection GEMM, BK=64 cross-product K-loop.
// 12 barrier-phases (vs 24), 96 MFMA/wave per phase. LDS 64 KB -> 2 blk/CU
// (same residency as BK=32; measured occupancy was ~25%).
// Bank fix for 128B rows: source-side row-parity XOR-4 chunk swizzle
// (dest stays lane-linear per m104); frag reads use kb ^ (row&1).
// Accumulation order identical to r9 -> bit-identical results.
// ---------------------------------------------------------------------------
__global__ __launch_bounds__(256, 2)
void gemm_qkvg_mfma(const unsigned short* __restrict__ xs,
                    const unsigned short* __restrict__ wt,
                    float* __restrict__ qws, float* __restrict__ kws,
                    float* __restrict__ vws, float* __restrict__ gws)
{
    __shared__ unsigned short Ah[128*64];
    __shared__ unsigned short Al[128*64];
    __shared__ unsigned short Bh[128*64];
    __shared__ unsigned short Bl[128*64];

    const int m0 = blockIdx.x * 128;
    const int n0 = blockIdx.y * 128;
    const int tid = threadIdx.x;
    const int lane = tid & 63, w = tid >> 6;
    const int wm = (w & 1) * 64, wn = (w >> 1) * 64;
    const int l15 = lane & 15, lq = lane >> 4;

    // staging: thread covers chunk f = j*256 + tid (j=0..3) of each buffer;
    // row = r8 + j*32, chunk-col c8 = tid&7, swizzled source col c8x.
    const int r8 = tid >> 3, c8 = tid & 7;
    const int c8x = c8 ^ ((r8 & 1) << 2);
    const unsigned short* xsrc[4];
    const unsigned short* bsrc[4];
    #pragma unroll
    for (int j = 0; j < 4; j++){
        xsrc[j] = xs + (size_t)(m0 + r8 + j*32) * KSPLIT + c8x*8;
        bsrc[j] = wt + (size_t)(n0 + r8 + j*32) * KSPLIT + c8x*8;
    }

    f32x4 acc[4][4];
    #pragma unroll
    for (int i = 0; i < 4; i++)
        #pragma unroll
        for (int j = 0; j < 4; j++)
            acc[i][j] = (f32x4){0.f, 0.f, 0.f, 0.f};

    #pragma unroll 1
    for (int ks = 0; ks < 12; ks++){
        const int o = ks*64;
        __syncthreads();
        #pragma unroll
        for (int j = 0; j < 4; j++){
            gload_lds16(xsrc[j] + o,      &Ah[j*2048 + tid*8]);
            gload_lds16(xsrc[j] + DM + o, &Al[j*2048 + tid*8]);
            gload_lds16(bsrc[j] + o,      &Bh[j*2048 + tid*8]);
            gload_lds16(bsrc[j] + DM + o, &Bl[j*2048 + tid*8]);
        }
        __syncthreads();

        // per-lane swizzled kb: row parity = l15&1
        const int swz = (l15 & 1) << 5;   // 0 or 32 ushorts
        #pragma unroll
        for (int kb = 0; kb < 2; kb++){
            const int ko = (kb*32) ^ swz;
            bf16x8 ah[4], al[4], bh[4], bl[4];
            #pragma unroll
            for (int im = 0; im < 4; im++){
                ah[im] = *(const bf16x8*)&Ah[(wm + im*16 + l15)*64 + ko + lq*8];
                al[im] = *(const bf16x8*)&Al[(wm + im*16 + l15)*64 + ko + lq*8];
            }
            #pragma unroll
            for (int jn = 0; jn < 4; jn++){
                bh[jn] = *(const bf16x8*)&Bh[(wn + jn*16 + l15)*64 + ko + lq*8];
                bl[jn] = *(const bf16x8*)&Bl[(wn + jn*16 + l15)*64 + ko + lq*8];
            }
            #pragma unroll
            for (int im = 0; im < 4; im++)
                #pragma unroll
                for (int jn = 0; jn < 4; jn++){
                    acc[im][jn] = __builtin_amdgcn_mfma_f32_16x16x32_bf16(
                        ah[im], bh[jn], acc[im][jn], 0, 0, 0);
                    acc[im][jn] = __builtin_amdgcn_mfma_f32_16x16x32_bf16(
                        ah[im], bl[jn], acc[im][jn], 0, 0, 0);
                    acc[im][jn] = __builtin_amdgcn_mfma_f32_16x16x32_bf16(
                        al[im], bh[jn], acc[im][jn], 0, 0, 0);
                }
        }
    }

    float* dst; int ld, cb, mode;
    const int bj = blockIdx.y;
    if      (bj < 2) { dst = qws; ld = DIMQ; cb = bj*128;       mode = 1; }
    else if (bj < 4) { dst = kws; ld = DIMQ; cb = (bj-2)*128;   mode = 1; }
    else if (bj < 6) { dst = vws; ld = DIMQ; cb = (bj-4)*128;   mode = 0; }
    else             { dst = gws; ld = DM;   cb = (bj-6)*128;   mode = 2; }

    #pragma unroll
    for (int im = 0; im < 4; im++){
        const int rb = m0 + wm + im*16 + lq*4;
        #pragma unroll
        for (int jn = 0; jn < 4; jn++){
            const int col = cb + wn + jn*16 + l15;
            f32x4 a = acc[im][jn];
            #pragma unroll
            for (int r = 0; r < 4; r++){
                float v0 = a[r];
                float vv = (mode == 1) ? act_elu1(v0)
                         : (mode == 2) ? act_sig(v0) : v0;
                dst[(size_t)(rb + r)*ld + col] = vv;
            }
        }
    }
}

// ---------------------------------------------------------------------------
// Kernel 2: chunk_state (blocks [0,512)) + split_wo (blocks [512,560)). (r9)
// ---------------------------------------------------------------------------
__global__ __launch_bounds__(256, 2)
void chunk_state_wo(const float* __restrict__ kws, const float* __restrict__ vws,
                    float* __restrict__ Sws,
                    const float* __restrict__ Wo, unsigned short* __restrict__ wot)
{
    __shared__ float Ks[64][64];
    __shared__ float Vt[64][68];
    __shared__ float T[64][65];

    const int blk = blockIdx.x;
    const int tid = threadIdx.x;

    if (blk >= NBH*NCHUNK) {                 // ---- split_wo tile ----
        const int i = blk - NBH*NCHUNK;
        const int n0 = (i % 12)*64, k0 = (i / 12)*64;
        const int lr = tid >> 4, lc = (tid & 15) * 4;
        #pragma unroll
        for (int ii = 0; ii < 4; ii++){
            int r = lr + ii*16;
            float4 v = *(const float4*)&Wo[(size_t)(k0+r)*DM + n0 + lc];
            T[r][lc+0]=v.x; T[r][lc+1]=v.y; T[r][lc+2]=v.z; T[r][lc+3]=v.w;
        }
        __syncthreads();
        const int rn = tid >> 2, kc = (tid & 3) * 16;
        unsigned short hb[16], lb[16];
        #pragma unroll
        for (int j = 0; j < 16; j++){
            float f = T[kc+j][rn];
            hb[j] = bf16_rne(f);
            float hf = bf2f(hb[j]);
            lb[j] = bf16_rne(f - hf);
        }
        size_t base = (size_t)(n0+rn)*KS2 + k0 + kc;
        #pragma unroll
        for (int q = 0; q < 4; q++){
            ushort4 hv = {hb[q*4],hb[q*4+1],hb[q*4+2],hb[q*4+3]};
            ushort4 lv = {lb[q*4],lb[q*4+1],lb[q*4+2],lb[q*4+3]};
            *(ushort4*)&wot[base + q*4] = hv;
            *(ushort4*)&wot[base + DIMQ + q*4] = lv;
        }
        return;
    }

    const int c = blk & (NCHUNK-1);
    const int bh = blk >> 6;
    const int b = bh >> 2, h = bh & 3;
    const int row0 = b*TSEQ + c*CHUNK;
    const int col0 = h*DHEAD;

    #pragma unroll
    for (int i = 0; i < 4; i++) {
        int flat = tid + i*256;
        int s = flat >> 4, dq = flat & 15;
        float4 k4 = *(const float4*)&kws[(size_t)(row0+s)*DIMQ + col0 + dq*4];
        *(float4*)&Ks[s][dq*4] = k4;
        float4 v4 = *(const float4*)&vws[(size_t)(row0+s)*DIMQ + col0 + dq*4];
        Vt[dq*4+0][s] = v4.x; Vt[dq*4+1][s] = v4.y;
        Vt[dq*4+2][s] = v4.z; Vt[dq*4+3][s] = v4.w;
    }
    __syncthreads();

    const int e = tid >> 2, d0 = (tid & 3) * 16;
    float4 a0 = {0,0,0,0}, a1 = {0,0,0,0}, a2 = {0,0,0,0}, a3 = {0,0,0,0};
    for (int s = 0; s < 64; s++) {
        float ve = Vt[e][s];
        fma4(a0, ve, *(const float4*)&Ks[s][d0+0]);
        fma4(a1, ve, *(const float4*)&Ks[s][d0+4]);
        fma4(a2, ve, *(const float4*)&Ks[s][d0+8]);
        fma4(a3, ve, *(const float4*)&Ks[s][d0+12]);
    }
    float* Sp = Sws + (size_t)blk * STATE;
    *(float4*)&Sp[e*64 + d0 + 0]  = a0;
    *(float4*)&Sp[e*64 + d0 + 4]  = a1;
    *(float4*)&Sp[e*64 + d0 + 8]  = a2;
    *(float4*)&Sp[e*64 + d0 + 12] = a3;

    if (tid < 64) {
        float z = 0.f;
        for (int s = 0; s < 64; s++) z += Ks[s][tid];
        Sp[4096 + tid] = z;
    }
}

// ---------------------------------------------------------------------------
// Kernel 3: exclusive prefix over chunks, register-resident. (r9)
// ---------------------------------------------------------------------------
__global__ __launch_bounds__(256)
void prefix_scan(const float* __restrict__ Sws, float* __restrict__ Pws)
{
    const int colg = blockIdx.x*256 + threadIdx.x;
    if (colg >= NBH*STATE) return;
    const int bh = colg / STATE;
    const int i = colg - bh*STATE;
    const size_t base = (size_t)bh * NCHUNK * STATE + i;
    const float* sp = Sws + base;
    float* pp = Pws + base;
    float v[NCHUNK];
    #pragma unroll
    for (int c = 0; c < NCHUNK; c++) v[c] = sp[(size_t)c * STATE];
    float run = 0.f;
    #pragma unroll
    for (int c = 0; c < NCHUNK; c++){
        pp[(size_t)c * STATE] = run;
        run += v[c];
    }
}

// ---------------------------------------------------------------------------
// Kernel 4: per-chunk output via MFMA (split-bf16 3-term). (r9)
// ---------------------------------------------------------------------------
__global__ __launch_bounds__(256, 2)
void chunk_out_mfma(const float* __restrict__ qws, const float* __restrict__ kws,
                    const float* __restrict__ vws, const float* __restrict__ Pws,
                    unsigned short* __restrict__ attn_s)
{
    __shared__ unsigned short Qh[64*STR],  Ql_[64*STR];
    __shared__ unsigned short VAh[64*STR], VAl[64*STR];
    __shared__ unsigned short Kth[64*STR], Ktl[64*STR];
    __shared__ unsigned short PT[2*64*STR];
    __shared__ float zP[64];
    __shared__ float dpart[64][4];
    __shared__ float dinv[64];
    float* Kcum = (float*)PT;

    const int blk = blockIdx.x;
    const int c = blk & (NCHUNK-1);
    const int bh = blk >> 6;
    const int b = bh >> 2, h = bh & 3;
    const int row0 = b*TSEQ + c*CHUNK;
    const int col0 = h*DHEAD;
    const int tid = threadIdx.x;
    const int lane = tid & 63, wv = tid >> 6;
    const int l15 = lane & 15, lq4 = lane >> 4;
    const int tb = wv * 16;
    const float* Pp = Pws + (size_t)blk * STATE;

    {
        const int r = tid >> 2, c0 = (tid & 3) * 16;
        unsigned short hh[16], ll[16];
        split16(&qws[(size_t)(row0+r)*DIMQ + col0 + c0], hh, ll);
        #pragma unroll
        for (int q = 0; q < 4; q++){
            *(ushort4*)&Qh [r*STR + c0 + q*4] = *(ushort4*)&hh[q*4];
            *(ushort4*)&Ql_[r*STR + c0 + q*4] = *(ushort4*)&ll[q*4];
        }
        split16(&vws[(size_t)(row0+r)*DIMQ + col0 + c0], hh, ll);
        #pragma unroll
        for (int q = 0; q < 4; q++){
            *(ushort4*)&VAh[r*STR + c0 + q*4] = *(ushort4*)&hh[q*4];
            *(ushort4*)&VAl[r*STR + c0 + q*4] = *(ushort4*)&ll[q*4];
        }
        split16(&kws[(size_t)(row0+r)*DIMQ + col0 + c0], hh, ll);
        #pragma unroll
        for (int j = 0; j < 16; j++){
            Kth[(c0+j)*STR + r] = hh[j];
            Ktl[(c0+j)*STR + r] = ll[j];
        }
        if (tid < 16) *(float4*)&zP[tid*4] = *(const float4*)&Pp[4096 + tid*4];
    }
    __syncthreads();   // B1

    bf16x8 qfh[2], qfl[2];
    #pragma unroll
    for (int kb = 0; kb < 2; kb++){
        qfh[kb] = *(const bf16x8*)&Qh [(tb + l15)*STR + kb*32 + lq4*8];
        qfl[kb] = *(const bf16x8*)&Ql_[(tb + l15)*STR + kb*32 + lq4*8];
    }
    f32x4 afr[4];
    #pragma unroll
    for (int st = 0; st < 4; st++){
        f32x4 a = (f32x4){0.f,0.f,0.f,0.f};
        #pragma unroll
        for (int kb = 0; kb < 2; kb++){
            bf16x8 vh_ = *(const bf16x8*)&VAh[(st*16 + l15)*STR + kb*32 + lq4*8];
            bf16x8 vl_ = *(const bf16x8*)&VAl[(st*16 + l15)*STR + kb*32 + lq4*8];
            a = __builtin_amdgcn_mfma_f32_16x16x32_bf16(qfh[kb], vh_, a, 0,0,0);
            a = __builtin_amdgcn_mfma_f32_16x16x32_bf16(qfh[kb], vl_, a, 0,0,0);
            a = __builtin_amdgcn_mfma_f32_16x16x32_bf16(qfl[kb], vh_, a, 0,0,0);
        }
        afr[st] = a;
    }

    if (tid < 64) {
        float run = 0.f;
        #pragma unroll
        for (int cb = 0; cb < 8; cb++){
            bf16x8 hh = *(const bf16x8*)&Kth[tid*STR + cb*8];
            bf16x8 ll = *(const bf16x8*)&Ktl[tid*STR + cb*8];
            #pragma unroll
            for (int j = 0; j < 8; j++){
                run += bf2f((unsigned short)hh[j]) + bf2f((unsigned short)ll[j]);
                Kcum[(cb*8+j)*68 + tid] = run;
            }
        }
    }
    __syncthreads();   // B2

    {
        const int t = tid >> 2, qq = tid & 3;
        bf16x8 qh0 = *(const bf16x8*)&Qh [t*STR + qq*16];
        bf16x8 qh1 = *(const bf16x8*)&Qh [t*STR + qq*16 + 8];
        bf16x8 ql0 = *(const bf16x8*)&Ql_[t*STR + qq*16];
        bf16x8 ql1 = *(const bf16x8*)&Ql_[t*STR + qq*16 + 8];
        float dsum = 0.f;
        #pragma unroll
        for (int j = 0; j < 8; j++){
            float qv = bf2f((unsigned short)qh0[j]) + bf2f((unsigned short)ql0[j]);
            dsum = fmaf(qv, Kcum[t*68 + qq*16 + j] + zP[qq*16 + j], dsum);
        }
        #pragma unroll
        for (int j = 0; j < 8; j++){
            float qv = bf2f((unsigned short)qh1[j]) + bf2f((unsigned short)ql1[j]);
            dsum = fmaf(qv, Kcum[t*68 + qq*16 + 8 + j] + zP[qq*16 + 8 + j], dsum);
        }
        dpart[t][qq] = dsum;
    }
    #pragma unroll
    for (int st = 0; st < 4; st++){
        #pragma unroll
        for (int r = 0; r < 4; r++){
            int tg = tb + lq4*4 + r;
            int sg = st*16 + l15;
            float av = (sg <= tg) ? afr[st][r] : 0.f;
            unsigned short hh = bf16_rne(av);
            unsigned short ll = bf16_rne(av - bf2f(hh));
            VAh[tg*STR + sg] = hh;
            VAl[tg*STR + sg] = ll;
        }
    }
    __syncthreads();   // B3

    if ((tid & 3) == 0) {
        int t = tid >> 2;
        float den = dpart[t][0] + dpart[t][1] + dpart[t][2] + dpart[t][3];
        dinv[t] = 1.f / fmaxf(den, 1e-6f);
    }
    {
        const int r = tid >> 2, c0 = (tid & 3) * 16;
        unsigned short hh[16], ll[16];
        split16(&Pp[r*64 + c0], hh, ll);
        #pragma unroll
        for (int j = 0; j < 16; j++){
            PT[(c0+j)*STR + r] = hh[j];
            PT[64*STR + (c0+j)*STR + r] = ll[j];
        }
    }
    __syncthreads();   // B4

    bf16x8 amh[2], aml[2];
    #pragma unroll
    for (int kb = 0; kb < 2; kb++){
        amh[kb] = *(const bf16x8*)&VAh[(tb + l15)*STR + kb*32 + lq4*8];
        aml[kb] = *(const bf16x8*)&VAl[(tb + l15)*STR + kb*32 + lq4*8];
    }
    #pragma unroll
    for (int dt = 0; dt < 4; dt++){
        f32x4 o = (f32x4){0.f,0.f,0.f,0.f};
        #pragma unroll
        for (int kb = 0; kb < 2; kb++){
            bf16x8 ph_ = *(const bf16x8*)&PT[(dt*16 + l15)*STR + kb*32 + lq4*8];
            bf16x8 pl_ = *(const bf16x8*)&PT[64*STR + (dt*16 + l15)*STR + kb*32 + lq4*8];
            bf16x8 kh_ = *(const bf16x8*)&Kth[(dt*16 + l15)*STR + kb*32 + lq4*8];
            bf16x8 kl_ = *(const bf16x8*)&Ktl[(dt*16 + l15)*STR + kb*32 + lq4*8];
            o = __builtin_amdgcn_mfma_f32_16x16x32_bf16(qfh[kb], ph_, o, 0,0,0);
            o = __builtin_amdgcn_mfma_f32_16x16x32_bf16(qfh[kb], pl_, o, 0,0,0);
            o = __builtin_amdgcn_mfma_f32_16x16x32_bf16(qfl[kb], ph_, o, 0,0,0);
            o = __builtin_amdgcn_mfma_f32_16x16x32_bf16(amh[kb], kh_, o, 0,0,0);
            o = __builtin_amdgcn_mfma_f32_16x16x32_bf16(amh[kb], kl_, o, 0,0,0);
            o = __builtin_amdgcn_mfma_f32_16x16x32_bf16(aml[kb], kh_, o, 0,0,0);
        }
        #pragma unroll
        for (int r = 0; r < 4; r++){
            int tg = tb + lq4*4 + r;
            float val = o[r] * dinv[tg];
            unsigned short hh = bf16_rne(val);
            unsigned short ll = bf16_rne(val - bf2f(hh));
            size_t base = (size_t)(row0 + tg)*KS2 + col0 + dt*16 + l15;
            attn_s[base] = hh;
            attn_s[base + DIMQ] = ll;
        }
    }
}

// ---------------------------------------------------------------------------
// Kernel 5: out = (attn @ Wo) * gate, split-bf16 MFMA, 128x128, grid (64,6). (r9)
// ---------------------------------------------------------------------------
__global__ __launch_bounds__(256, 2)
void gemm_out_mfma(const unsigned short* __restrict__ attn_s,
                   const unsigned short* __restrict__ wot,
                   const float* __restrict__ gws, float* __restrict__ out)
{
    __shared__ unsigned short Ah[128*32];
    __shared__ unsigned short Al[128*32];
    __shared__ unsigned short Bh[128*32];
    __shared__ unsigned short Bl[128*32];

    const int m0 = blockIdx.x * 128;
    const int n0 = blockIdx.y * 128;
    const int tid = threadIdx.x;
    const int lane = tid & 63, w = tid >> 6;
    const int wm = (w & 1) * 64, wn = (w >> 1) * 64;
    const int l15 = lane & 15, lq = lane >> 4;

    const int srow = tid >> 2, scq = tid & 3;
    const unsigned short* ar0 = attn_s + (size_t)(m0+srow)   * KS2 + scq*8;
    const unsigned short* ar1 = attn_s + (size_t)(m0+srow+64)* KS2 + scq*8;
    const unsigned short* br0 = wot + (size_t)(n0+srow)   * KS2 + scq*8;
    const unsigned short* br1 = wot + (size_t)(n0+srow+64)* KS2 + scq*8;

    f32x4 acc[4][4];
    #pragma unroll
    for (int i = 0; i < 4; i++)
        #pragma unroll
        for (int j = 0; j < 4; j++)
            acc[i][j] = (f32x4){0.f, 0.f, 0.f, 0.f};

    #pragma unroll 1
    for (int ks = 0; ks < 8; ks++){
        const int o = ks*32;
        __syncthreads();
        gload_lds16(ar0 + o,        &Ah[tid*8]);
        gload_lds16(ar1 + o,        &Ah[2048 + tid*8]);
        gload_lds16(ar0 + DIMQ + o, &Al[tid*8]);
        gload_lds16(ar1 + DIMQ + o, &Al[2048 + tid*8]);
        gload_lds16(br0 + o,        &Bh[tid*8]);
        gload_lds16(br1 + o,        &Bh[2048 + tid*8]);
        gload_lds16(br0 + DIMQ + o, &Bl[tid*8]);
        gload_lds16(br1 + DIMQ + o, &Bl[2048 + tid*8]);
        __syncthreads();

        bf16x8 ah[4], al[4], bh[4], bl[4];
        #pragma unroll
        for (int im = 0; im < 4; im++){
            ah[im] = *(const bf16x8*)&Ah[(wm + im*16 + l15)*32 + lq*8];
            al[im] = *(const bf16x8*)&Al[(wm + im*16 + l15)*32 + lq*8];
        }
        #pragma unroll
        for (int jn = 0; jn < 4; jn++){
            bh[jn] = *(const bf16x8*)&Bh[(wn + jn*16 + l15)*32 + lq*8];
            bl[jn] = *(const bf16x8*)&Bl[(wn + jn*16 + l15)*32 + lq*8];
        }
        #pragma unroll
        for (int im = 0; im < 4; im++)
            #pragma unroll
            for (int jn = 0; jn < 4; jn++){
                acc[im][jn] = __builtin_amdgcn_mfma_f32_16x16x32_bf16(
                    ah[im], bh[jn], acc[im][jn], 0, 0, 0);
                acc[im][jn] = __builtin_amdgcn_mfma_f32_16x16x32_bf16(
                    ah[im], bl[jn], acc[im][jn], 0, 0, 0);
                acc[im][jn] = __builtin_amdgcn_mfma_f32_16x16x32_bf16(
                    al[im], bh[jn], acc[im][jn], 0, 0, 0);
            }
    }

    #pragma unroll
    for (int im = 0; im < 4; im++){
        const int rb = m0 + wm + im*16 + lq*4;
        #pragma unroll
        for (int jn = 0; jn < 4; jn++){
            const int col = n0 + wn + jn*16 + l15;
            f32x4 a = acc[im][jn];
            #pragma unroll
            for (int r = 0; r < 4; r++){
                size_t idx = (size_t)(rb + r)*DM + col;
                out[idx] = a[r] * gws[idx];
            }
        }
    }
}

// ---------------------------------------------------------------------------
extern "C" void kernel_launch(void* const* d_in, const int* in_sizes, int n_in,
                              void* d_out, int out_size, void* d_ws, size_t ws_size,
                              hipStream_t stream)
{
    const float* x  = (const float*)d_in[0];
    const float* Wq = (const float*)d_in[1];
    const float* Wk = (const float*)d_in[2];
    const float* Wv = (const float*)d_in[3];
    const float* Wo = (const float*)d_in[4];
    const float* Wg = (const float*)d_in[5];
    float* out = (float*)d_out;

    float* w    = (float*)d_ws;
    float* qws  = w;                                   // 8192*256 f32
    float* kws  = qws + (size_t)MROWS*DIMQ;            // 8192*256 f32
    float* vws  = kws + (size_t)MROWS*DIMQ;            // 8192*256 f32
    float* gws  = vws + (size_t)MROWS*DIMQ;            // 8192*768 f32
    float* region = gws + (size_t)MROWS*DM;            // reused region (28.5 MB)
    unsigned short* xs = (unsigned short*)region;
    unsigned short* wt = xs + (size_t)MROWS*KSPLIT;
    float* Sws = region;
    float* Pws = Sws + (size_t)NBH*NCHUNK*STATE;
    unsigned short* attn_s = (unsigned short*)(Pws + (size_t)NBH*NCHUNK*STATE);
    unsigned short* wot = attn_s + (size_t)MROWS*KS2;
    // high-water: 78.8 MB (same as verified rounds 2-9)

    hipLaunchKernelGGL(prep, dim3(MROWS + 288), dim3(256), 0, stream,
                       x, Wq, Wk, Wv, Wg, xs, wt);
    hipLaunchKernelGGL(gemm_qkvg_mfma, dim3(64,12), dim3(256), 0, stream,
                       xs, wt, qws, kws, vws, gws);
    hipLaunchKernelGGL(chunk_state_wo, dim3(NBH*NCHUNK + 48), dim3(256), 0, stream,
                       kws, vws, Sws, Wo, wot);
    hipLaunchKernelGGL(prefix_scan, dim3((NBH*STATE + 255)/256), dim3(256), 0, stream,
                       Sws, Pws);
    hipLaunchKernelGGL(chunk_out_mfma, dim3(NBH*NCHUNK), dim3(256), 0, stream,
                       qws, kws, vws, Pws, attn_s);
    hipLaunchKernelGGL(gemm_out_mfma, dim3(64,6), dim3(256), 0, stream,
                       attn_s, wot, gws, out);
}

// Round 11
// 193.734 us; speedup vs baseline: 1.0523x; 1.0523x over previous
//
#include <hip/hip_runtime.h>
#include <math.h>

#define BATCH 2
#define TSEQ 4096
#define DM 768
#define HEADS 4
#define DHEAD 64
#define DIMQ 256                  // HEADS*DHEAD
#define MROWS (BATCH*TSEQ)        // 8192
#define CHUNK 64
#define NCHUNK (TSEQ/CHUNK)       // 64
#define NBH (BATCH*HEADS)         // 8
#define STATE (DHEAD*DHEAD + DHEAD)  // 4160
#define KSPLIT (DM*2)             // 1536 stored k-cols for x/wt: [hi 768 | lo 768]
#define KS2 (DIMQ*2)              // 512 stored k-cols for attn/wot: [hi 256 | lo 256]
#define STR 72                    // LDS bf16 row stride: 144B (16B-aligned, bank-stride 4)

typedef __attribute__((ext_vector_type(8))) short bf16x8;
typedef __attribute__((ext_vector_type(4))) float f32x4;

__device__ __forceinline__ float act_elu1(float x){ return x > 0.f ? x + 1.f : expf(x); }
__device__ __forceinline__ float act_sig(float x){ return 1.f/(1.f + expf(-x)); }

__device__ __forceinline__ void fma4(float4& o, float a, const float4& b){
    o.x = fmaf(a, b.x, o.x); o.y = fmaf(a, b.y, o.y);
    o.z = fmaf(a, b.z, o.z); o.w = fmaf(a, b.w, o.w);
}

// round-to-nearest-even fp32 -> bf16
__device__ __forceinline__ unsigned short bf16_rne(float f){
    unsigned u = __float_as_uint(f);
    u += 0x7FFFu + ((u >> 16) & 1u);
    return (unsigned short)(u >> 16);
}
__device__ __forceinline__ float bf2f(unsigned short h){
    return __uint_as_float(((unsigned)h) << 16);
}

// NOTE: LDS dest is wave-uniform base + lane*16B (m104/m108).
__device__ __forceinline__ void gload_lds16(const void* g, void* l){
    __builtin_amdgcn_global_load_lds(
        (const __attribute__((address_space(1))) unsigned char*)g,
        (__attribute__((address_space(3))) unsigned char*)l, 16, 0, 0);
}

// split 16 consecutive floats into bf16 hi/lo
__device__ __forceinline__ void split16(const float* __restrict__ src,
                                        unsigned short* h, unsigned short* l){
    #pragma unroll
    for (int j4 = 0; j4 < 4; j4++){
        float4 v = *(const float4*)(src + j4*4);
        float vv[4] = {v.x, v.y, v.z, v.w};
        #pragma unroll
        for (int j = 0; j < 4; j++){
            h[j4*4+j] = bf16_rne(vv[j]);
            float hf = bf2f(h[j4*4+j]);
            l[j4*4+j] = bf16_rne(vv[j] - hf);
        }
    }
}

// ---------------------------------------------------------------------------
// Kernel 0: merged prep (coalesced x-split).
// ---------------------------------------------------------------------------
__global__ __launch_bounds__(256)
void prep(const float* __restrict__ x,
          const float* __restrict__ Wq, const float* __restrict__ Wk,
          const float* __restrict__ Wv, const float* __restrict__ Wg,
          unsigned short* __restrict__ xs, unsigned short* __restrict__ wt)
{
    __shared__ float T[64][65];
    const int bid = blockIdx.x;
    const int t = threadIdx.x;

    if (bid < MROWS) {                       // ---- x split ----
        if (t < 192) {
            const int r = bid;
            const int c = t * 4;
            float4 v = *(const float4*)&x[(size_t)r*DM + c];
            float vv[4] = {v.x, v.y, v.z, v.w};
            unsigned short h[4], l[4];
            #pragma unroll
            for (int j = 0; j < 4; j++){
                h[j] = bf16_rne(vv[j]);
                float hf = bf2f(h[j]);
                l[j] = bf16_rne(vv[j] - hf);
            }
            ushort4 h4 = {h[0],h[1],h[2],h[3]}, l4 = {l[0],l[1],l[2],l[3]};
            *(ushort4*)&xs[(size_t)r*KSPLIT + c] = h4;
            *(ushort4*)&xs[(size_t)r*KSPLIT + DM + c] = l4;
        }
        return;
    }

    const int i = bid - MROWS;
    const int n0 = (i % 24)*64, k0 = (i / 24)*64;
    const float* W; int ldw, c0;
    if      (n0 < 256) { W = Wq; ldw = DIMQ; c0 = n0;       }
    else if (n0 < 512) { W = Wk; ldw = DIMQ; c0 = n0 - 256; }
    else if (n0 < 768) { W = Wv; ldw = DIMQ; c0 = n0 - 512; }
    else               { W = Wg; ldw = DM;   c0 = n0 - 768; }

    const int lr = t >> 4, lc = (t & 15) * 4;
    #pragma unroll
    for (int ii = 0; ii < 4; ii++){
        int r = lr + ii*16;
        float4 v = *(const float4*)&W[(size_t)(k0+r)*ldw + c0 + lc];
        T[r][lc+0]=v.x; T[r][lc+1]=v.y; T[r][lc+2]=v.z; T[r][lc+3]=v.w;
    }
    __syncthreads();
    const int rn = t >> 2, kc = (t & 3) * 16;
    unsigned short hb[16], lb[16];
    #pragma unroll
    for (int j = 0; j < 16; j++){
        float f = T[kc+j][rn];
        hb[j] = bf16_rne(f);
        float hf = bf2f(hb[j]);
        lb[j] = bf16_rne(f - hf);
    }
    size_t base = (size_t)(n0+rn)*KSPLIT + k0 + kc;
    #pragma unroll
    for (int q = 0; q < 4; q++){
        ushort4 hv = {hb[q*4],hb[q*4+1],hb[q*4+2],hb[q*4+3]};
        ushort4 lv = {lb[q*4],lb[q*4+1],lb[q*4+2],lb[q*4+3]};
        *(ushort4*)&wt[base + q*4] = hv;
        *(ushort4*)&wt[base + DM + q*4] = lv;
    }
}

// ---------------------------------------------------------------------------
// Kernel 1: fused projection GEMM, BK=32 cross-product K-loop (r9 sweet spot:
// 32 KB LDS, 2+ blocks/CU, conflict-free frag reads — BK=64 regressed, r10).
// ---------------------------------------------------------------------------
__global__ __launch_bounds__(256, 2)
void gemm_qkvg_mfma(const unsigned short* __restrict__ xs,
                    const unsigned short* __restrict__ wt,
                    float* __restrict__ qws, float* __restrict__ kws,
                    float* __restrict__ vws, float* __restrict__ gws)
{
    __shared__ unsigned short Ah[128*32];
    __shared__ unsigned short Al[128*32];
    __shared__ unsigned short Bh[128*32];
    __shared__ unsigned short Bl[128*32];

    const int m0 = blockIdx.x * 128;
    const int n0 = blockIdx.y * 128;
    const int tid = threadIdx.x;
    const int lane = tid & 63, w = tid >> 6;
    const int wm = (w & 1) * 64, wn = (w >> 1) * 64;
    const int l15 = lane & 15, lq = lane >> 4;

    const int srow = tid >> 2, scq = tid & 3;
    const unsigned short* xr0 = xs + (size_t)(m0+srow)   * KSPLIT + scq*8;
    const unsigned short* xr1 = xs + (size_t)(m0+srow+64)* KSPLIT + scq*8;
    const unsigned short* br0 = wt + (size_t)(n0+srow)   * KSPLIT + scq*8;
    const unsigned short* br1 = wt + (size_t)(n0+srow+64)* KSPLIT + scq*8;

    f32x4 acc[4][4];
    #pragma unroll
    for (int i = 0; i < 4; i++)
        #pragma unroll
        for (int j = 0; j < 4; j++)
            acc[i][j] = (f32x4){0.f, 0.f, 0.f, 0.f};

    #pragma unroll 1
    for (int ks = 0; ks < 24; ks++){
        const int o = ks*32;
        __syncthreads();
        gload_lds16(xr0 + o,      &Ah[tid*8]);
        gload_lds16(xr1 + o,      &Ah[2048 + tid*8]);
        gload_lds16(xr0 + DM + o, &Al[tid*8]);
        gload_lds16(xr1 + DM + o, &Al[2048 + tid*8]);
        gload_lds16(br0 + o,      &Bh[tid*8]);
        gload_lds16(br1 + o,      &Bh[2048 + tid*8]);
        gload_lds16(br0 + DM + o, &Bl[tid*8]);
        gload_lds16(br1 + DM + o, &Bl[2048 + tid*8]);
        __syncthreads();

        bf16x8 ah[4], al[4], bh[4], bl[4];
        #pragma unroll
        for (int im = 0; im < 4; im++){
            ah[im] = *(const bf16x8*)&Ah[(wm + im*16 + l15)*32 + lq*8];
            al[im] = *(const bf16x8*)&Al[(wm + im*16 + l15)*32 + lq*8];
        }
        #pragma unroll
        for (int jn = 0; jn < 4; jn++){
            bh[jn] = *(const bf16x8*)&Bh[(wn + jn*16 + l15)*32 + lq*8];
            bl[jn] = *(const bf16x8*)&Bl[(wn + jn*16 + l15)*32 + lq*8];
        }
        #pragma unroll
        for (int im = 0; im < 4; im++)
            #pragma unroll
            for (int jn = 0; jn < 4; jn++){
                acc[im][jn] = __builtin_amdgcn_mfma_f32_16x16x32_bf16(
                    ah[im], bh[jn], acc[im][jn], 0, 0, 0);
                acc[im][jn] = __builtin_amdgcn_mfma_f32_16x16x32_bf16(
                    ah[im], bl[jn], acc[im][jn], 0, 0, 0);
                acc[im][jn] = __builtin_amdgcn_mfma_f32_16x16x32_bf16(
                    al[im], bh[jn], acc[im][jn], 0, 0, 0);
            }
    }

    float* dst; int ld, cb, mode;
    const int bj = blockIdx.y;
    if      (bj < 2) { dst = qws; ld = DIMQ; cb = bj*128;       mode = 1; }
    else if (bj < 4) { dst = kws; ld = DIMQ; cb = (bj-2)*128;   mode = 1; }
    else if (bj < 6) { dst = vws; ld = DIMQ; cb = (bj-4)*128;   mode = 0; }
    else             { dst = gws; ld = DM;   cb = (bj-6)*128;   mode = 2; }

    #pragma unroll
    for (int im = 0; im < 4; im++){
        const int rb = m0 + wm + im*16 + lq*4;
        #pragma unroll
        for (int jn = 0; jn < 4; jn++){
            const int col = cb + wn + jn*16 + l15;
            f32x4 a = acc[im][jn];
            #pragma unroll
            for (int r = 0; r < 4; r++){
                float v0 = a[r];
                float vv = (mode == 1) ? act_elu1(v0)
                         : (mode == 2) ? act_sig(v0) : v0;
                dst[(size_t)(rb + r)*ld + col] = vv;
            }
        }
    }
}

// ---------------------------------------------------------------------------
// Kernel 2: chunk_state (blocks [0,512)) + split_wo (blocks [512,560)).
// ---------------------------------------------------------------------------
__global__ __launch_bounds__(256, 2)
void chunk_state_wo(const float* __restrict__ kws, const float* __restrict__ vws,
                    float* __restrict__ Sws,
                    const float* __restrict__ Wo, unsigned short* __restrict__ wot)
{
    __shared__ float Ks[64][64];
    __shared__ float Vt[64][68];
    __shared__ float T[64][65];

    const int blk = blockIdx.x;
    const int tid = threadIdx.x;

    if (blk >= NBH*NCHUNK) {                 // ---- split_wo tile ----
        const int i = blk - NBH*NCHUNK;
        const int n0 = (i % 12)*64, k0 = (i / 12)*64;
        const int lr = tid >> 4, lc = (tid & 15) * 4;
        #pragma unroll
        for (int ii = 0; ii < 4; ii++){
            int r = lr + ii*16;
            float4 v = *(const float4*)&Wo[(size_t)(k0+r)*DM + n0 + lc];
            T[r][lc+0]=v.x; T[r][lc+1]=v.y; T[r][lc+2]=v.z; T[r][lc+3]=v.w;
        }
        __syncthreads();
        const int rn = tid >> 2, kc = (tid & 3) * 16;
        unsigned short hb[16], lb[16];
        #pragma unroll
        for (int j = 0; j < 16; j++){
            float f = T[kc+j][rn];
            hb[j] = bf16_rne(f);
            float hf = bf2f(hb[j]);
            lb[j] = bf16_rne(f - hf);
        }
        size_t base = (size_t)(n0+rn)*KS2 + k0 + kc;
        #pragma unroll
        for (int q = 0; q < 4; q++){
            ushort4 hv = {hb[q*4],hb[q*4+1],hb[q*4+2],hb[q*4+3]};
            ushort4 lv = {lb[q*4],lb[q*4+1],lb[q*4+2],lb[q*4+3]};
            *(ushort4*)&wot[base + q*4] = hv;
            *(ushort4*)&wot[base + DIMQ + q*4] = lv;
        }
        return;
    }

    const int c = blk & (NCHUNK-1);
    const int bh = blk >> 6;
    const int b = bh >> 2, h = bh & 3;
    const int row0 = b*TSEQ + c*CHUNK;
    const int col0 = h*DHEAD;

    #pragma unroll
    for (int i = 0; i < 4; i++) {
        int flat = tid + i*256;
        int s = flat >> 4, dq = flat & 15;
        float4 k4 = *(const float4*)&kws[(size_t)(row0+s)*DIMQ + col0 + dq*4];
        *(float4*)&Ks[s][dq*4] = k4;
        float4 v4 = *(const float4*)&vws[(size_t)(row0+s)*DIMQ + col0 + dq*4];
        Vt[dq*4+0][s] = v4.x; Vt[dq*4+1][s] = v4.y;
        Vt[dq*4+2][s] = v4.z; Vt[dq*4+3][s] = v4.w;
    }
    __syncthreads();

    const int e = tid >> 2, d0 = (tid & 3) * 16;
    float4 a0 = {0,0,0,0}, a1 = {0,0,0,0}, a2 = {0,0,0,0}, a3 = {0,0,0,0};
    for (int s = 0; s < 64; s++) {
        float ve = Vt[e][s];
        fma4(a0, ve, *(const float4*)&Ks[s][d0+0]);
        fma4(a1, ve, *(const float4*)&Ks[s][d0+4]);
        fma4(a2, ve, *(const float4*)&Ks[s][d0+8]);
        fma4(a3, ve, *(const float4*)&Ks[s][d0+12]);
    }
    float* Sp = Sws + (size_t)blk * STATE;
    *(float4*)&Sp[e*64 + d0 + 0]  = a0;
    *(float4*)&Sp[e*64 + d0 + 4]  = a1;
    *(float4*)&Sp[e*64 + d0 + 8]  = a2;
    *(float4*)&Sp[e*64 + d0 + 12] = a3;

    if (tid < 64) {
        float z = 0.f;
        for (int s = 0; s < 64; s++) z += Ks[s][tid];
        Sp[4096 + tid] = z;
    }
}

// ---------------------------------------------------------------------------
// Kernel 3: exclusive prefix over chunks, register-resident.
// ---------------------------------------------------------------------------
__global__ __launch_bounds__(256)
void prefix_scan(const float* __restrict__ Sws, float* __restrict__ Pws)
{
    const int colg = blockIdx.x*256 + threadIdx.x;
    if (colg >= NBH*STATE) return;
    const int bh = colg / STATE;
    const int i = colg - bh*STATE;
    const size_t base = (size_t)bh * NCHUNK * STATE + i;
    const float* sp = Sws + base;
    float* pp = Pws + base;
    float v[NCHUNK];
    #pragma unroll
    for (int c = 0; c < NCHUNK; c++) v[c] = sp[(size_t)c * STATE];
    float run = 0.f;
    #pragma unroll
    for (int c = 0; c < NCHUNK; c++){
        pp[(size_t)c * STATE] = run;
        run += v[c];
    }
}

// ---------------------------------------------------------------------------
// Kernel 4: per-chunk output via MFMA (split-bf16 3-term).
// ---------------------------------------------------------------------------
__global__ __launch_bounds__(256, 2)
void chunk_out_mfma(const float* __restrict__ qws, const float* __restrict__ kws,
                    const float* __restrict__ vws, const float* __restrict__ Pws,
                    unsigned short* __restrict__ attn_s)
{
    __shared__ unsigned short Qh[64*STR],  Ql_[64*STR];
    __shared__ unsigned short VAh[64*STR], VAl[64*STR];
    __shared__ unsigned short Kth[64*STR], Ktl[64*STR];
    __shared__ unsigned short PT[2*64*STR];
    __shared__ float zP[64];
    __shared__ float dpart[64][4];
    __shared__ float dinv[64];
    float* Kcum = (float*)PT;

    const int blk = blockIdx.x;
    const int c = blk & (NCHUNK-1);
    const int bh = blk >> 6;
    const int b = bh >> 2, h = bh & 3;
    const int row0 = b*TSEQ + c*CHUNK;
    const int col0 = h*DHEAD;
    const int tid = threadIdx.x;
    const int lane = tid & 63, wv = tid >> 6;
    const int l15 = lane & 15, lq4 = lane >> 4;
    const int tb = wv * 16;
    const float* Pp = Pws + (size_t)blk * STATE;

    {
        const int r = tid >> 2, c0 = (tid & 3) * 16;
        unsigned short hh[16], ll[16];
        split16(&qws[(size_t)(row0+r)*DIMQ + col0 + c0], hh, ll);
        #pragma unroll
        for (int q = 0; q < 4; q++){
            *(ushort4*)&Qh [r*STR + c0 + q*4] = *(ushort4*)&hh[q*4];
            *(ushort4*)&Ql_[r*STR + c0 + q*4] = *(ushort4*)&ll[q*4];
        }
        split16(&vws[(size_t)(row0+r)*DIMQ + col0 + c0], hh, ll);
        #pragma unroll
        for (int q = 0; q < 4; q++){
            *(ushort4*)&VAh[r*STR + c0 + q*4] = *(ushort4*)&hh[q*4];
            *(ushort4*)&VAl[r*STR + c0 + q*4] = *(ushort4*)&ll[q*4];
        }
        split16(&kws[(size_t)(row0+r)*DIMQ + col0 + c0], hh, ll);
        #pragma unroll
        for (int j = 0; j < 16; j++){
            Kth[(c0+j)*STR + r] = hh[j];
            Ktl[(c0+j)*STR + r] = ll[j];
        }
        if (tid < 16) *(float4*)&zP[tid*4] = *(const float4*)&Pp[4096 + tid*4];
    }
    __syncthreads();   // B1

    bf16x8 qfh[2], qfl[2];
    #pragma unroll
    for (int kb = 0; kb < 2; kb++){
        qfh[kb] = *(const bf16x8*)&Qh [(tb + l15)*STR + kb*32 + lq4*8];
        qfl[kb] = *(const bf16x8*)&Ql_[(tb + l15)*STR + kb*32 + lq4*8];
    }
    f32x4 afr[4];
    #pragma unroll
    for (int st = 0; st < 4; st++){
        f32x4 a = (f32x4){0.f,0.f,0.f,0.f};
        #pragma unroll
        for (int kb = 0; kb < 2; kb++){
            bf16x8 vh_ = *(const bf16x8*)&VAh[(st*16 + l15)*STR + kb*32 + lq4*8];
            bf16x8 vl_ = *(const bf16x8*)&VAl[(st*16 + l15)*STR + kb*32 + lq4*8];
            a = __builtin_amdgcn_mfma_f32_16x16x32_bf16(qfh[kb], vh_, a, 0,0,0);
            a = __builtin_amdgcn_mfma_f32_16x16x32_bf16(qfh[kb], vl_, a, 0,0,0);
            a = __builtin_amdgcn_mfma_f32_16x16x32_bf16(qfl[kb], vh_, a, 0,0,0);
        }
        afr[st] = a;
    }

    if (tid < 64) {
        float run = 0.f;
        #pragma unroll
        for (int cb = 0; cb < 8; cb++){
            bf16x8 hh = *(const bf16x8*)&Kth[tid*STR + cb*8];
            bf16x8 ll = *(const bf16x8*)&Ktl[tid*STR + cb*8];
            #pragma unroll
            for (int j = 0; j < 8; j++){
                run += bf2f((unsigned short)hh[j]) + bf2f((unsigned short)ll[j]);
                Kcum[(cb*8+j)*68 + tid] = run;
            }
        }
    }
    __syncthreads();   // B2

    {
        const int t = tid >> 2, qq = tid & 3;
        bf16x8 qh0 = *(const bf16x8*)&Qh [t*STR + qq*16];
        bf16x8 qh1 = *(const bf16x8*)&Qh [t*STR + qq*16 + 8];
        bf16x8 ql0 = *(const bf16x8*)&Ql_[t*STR + qq*16];
        bf16x8 ql1 = *(const bf16x8*)&Ql_[t*STR + qq*16 + 8];
        float dsum = 0.f;
        #pragma unroll
        for (int j = 0; j < 8; j++){
            float qv = bf2f((unsigned short)qh0[j]) + bf2f((unsigned short)ql0[j]);
            dsum = fmaf(qv, Kcum[t*68 + qq*16 + j] + zP[qq*16 + j], dsum);
        }
        #pragma unroll
        for (int j = 0; j < 8; j++){
            float qv = bf2f((unsigned short)qh1[j]) + bf2f((unsigned short)ql1[j]);
            dsum = fmaf(qv, Kcum[t*68 + qq*16 + 8 + j] + zP[qq*16 + 8 + j], dsum);
        }
        dpart[t][qq] = dsum;
    }
    #pragma unroll
    for (int st = 0; st < 4; st++){
        #pragma unroll
        for (int r = 0; r < 4; r++){
            int tg = tb + lq4*4 + r;
            int sg = st*16 + l15;
            float av = (sg <= tg) ? afr[st][r] : 0.f;
            unsigned short hh = bf16_rne(av);
            unsigned short ll = bf16_rne(av - bf2f(hh));
            VAh[tg*STR + sg] = hh;
            VAl[tg*STR + sg] = ll;
        }
    }
    __syncthreads();   // B3

    if ((tid & 3) == 0) {
        int t = tid >> 2;
        float den = dpart[t][0] + dpart[t][1] + dpart[t][2] + dpart[t][3];
        dinv[t] = 1.f / fmaxf(den, 1e-6f);
    }
    {
        const int r = tid >> 2, c0 = (tid & 3) * 16;
        unsigned short hh[16], ll[16];
        split16(&Pp[r*64 + c0], hh, ll);
        #pragma unroll
        for (int j = 0; j < 16; j++){
            PT[(c0+j)*STR + r] = hh[j];
            PT[64*STR + (c0+j)*STR + r] = ll[j];
        }
    }
    __syncthreads();   // B4

    bf16x8 amh[2], aml[2];
    #pragma unroll
    for (int kb = 0; kb < 2; kb++){
        amh[kb] = *(const bf16x8*)&VAh[(tb + l15)*STR + kb*32 + lq4*8];
        aml[kb] = *(const bf16x8*)&VAl[(tb + l15)*STR + kb*32 + lq4*8];
    }
    #pragma unroll
    for (int dt = 0; dt < 4; dt++){
        f32x4 o = (f32x4){0.f,0.f,0.f,0.f};
        #pragma unroll
        for (int kb = 0; kb < 2; kb++){
            bf16x8 ph_ = *(const bf16x8*)&PT[(dt*16 + l15)*STR + kb*32 + lq4*8];
            bf16x8 pl_ = *(const bf16x8*)&PT[64*STR + (dt*16 + l15)*STR + kb*32 + lq4*8];
            bf16x8 kh_ = *(const bf16x8*)&Kth[(dt*16 + l15)*STR + kb*32 + lq4*8];
            bf16x8 kl_ = *(const bf16x8*)&Ktl[(dt*16 + l15)*STR + kb*32 + lq4*8];
            o = __builtin_amdgcn_mfma_f32_16x16x32_bf16(qfh[kb], ph_, o, 0,0,0);
            o = __builtin_amdgcn_mfma_f32_16x16x32_bf16(qfh[kb], pl_, o, 0,0,0);
            o = __builtin_amdgcn_mfma_f32_16x16x32_bf16(qfl[kb], ph_, o, 0,0,0);
            o = __builtin_amdgcn_mfma_f32_16x16x32_bf16(amh[kb], kh_, o, 0,0,0);
            o = __builtin_amdgcn_mfma_f32_16x16x32_bf16(amh[kb], kl_, o, 0,0,0);
            o = __builtin_amdgcn_mfma_f32_16x16x32_bf16(aml[kb], kh_, o, 0,0,0);
        }
        #pragma unroll
        for (int r = 0; r < 4; r++){
            int tg = tb + lq4*4 + r;
            float val = o[r] * dinv[tg];
            unsigned short hh = bf16_rne(val);
            unsigned short ll = bf16_rne(val - bf2f(hh));
            size_t base = (size_t)(row0 + tg)*KS2 + col0 + dt*16 + l15;
            attn_s[base] = hh;
            attn_s[base + DIMQ] = ll;
        }
    }
}

// ---------------------------------------------------------------------------
// Kernel 5: out = (attn @ Wo) * gate, split-bf16 MFMA, 128x128, grid (64,6).
// ---------------------------------------------------------------------------
__global__ __launch_bounds__(256, 2)
void gemm_out_mfma(const unsigned short* __restrict__ attn_s,
                   const unsigned short* __restrict__ wot,
                   const float* __restrict__ gws, float* __restrict__ out)
{
    __shared__ unsigned short Ah[128*32];
    __shared__ unsigned short Al[128*32];
    __shared__ unsigned short Bh[128*32];
    __shared__ unsigned short Bl[128*32];

    const int m0 = blockIdx.x * 128;
    const int n0 = blockIdx.y * 128;
    const int tid = threadIdx.x;
    const int lane = tid & 63, w = tid >> 6;
    const int wm = (w & 1) * 64, wn = (w >> 1) * 64;
    const int l15 = lane & 15, lq = lane >> 4;

    const int srow = tid >> 2, scq = tid & 3;
    const unsigned short* ar0 = attn_s + (size_t)(m0+srow)   * KS2 + scq*8;
    const unsigned short* ar1 = attn_s + (size_t)(m0+srow+64)* KS2 + scq*8;
    const unsigned short* br0 = wot + (size_t)(n0+srow)   * KS2 + scq*8;
    const unsigned short* br1 = wot + (size_t)(n0+srow+64)* KS2 + scq*8;

    f32x4 acc[4][4];
    #pragma unroll
    for (int i = 0; i < 4; i++)
        #pragma unroll
        for (int j = 0; j < 4; j++)
            acc[i][j] = (f32x4){0.f, 0.f, 0.f, 0.f};

    #pragma unroll 1
    for (int ks = 0; ks < 8; ks++){
        const int o = ks*32;
        __syncthreads();
        gload_lds16(ar0 + o,        &Ah[tid*8]);
        gload_lds16(ar1 + o,        &Ah[2048 + tid*8]);
        gload_lds16(ar0 + DIMQ + o, &Al[tid*8]);
        gload_lds16(ar1 + DIMQ + o, &Al[2048 + tid*8]);
        gload_lds16(br0 + o,        &Bh[tid*8]);
        gload_lds16(br1 + o,        &Bh[2048 + tid*8]);
        gload_lds16(br0 + DIMQ + o, &Bl[tid*8]);
        gload_lds16(br1 + DIMQ + o, &Bl[2048 + tid*8]);
        __syncthreads();

        bf16x8 ah[4], al[4], bh[4], bl[4];
        #pragma unroll
        for (int im = 0; im < 4; im++){
            ah[im] = *(const bf16x8*)&Ah[(wm + im*16 + l15)*32 + lq*8];
            al[im] = *(const bf16x8*)&Al[(wm + im*16 + l15)*32 + lq*8];
        }
        #pragma unroll
        for (int jn = 0; jn < 4; jn++){
            bh[jn] = *(const bf16x8*)&Bh[(wn + jn*16 + l15)*32 + lq*8];
            bl[jn] = *(const bf16x8*)&Bl[(wn + jn*16 + l15)*32 + lq*8];
        }
        #pragma unroll
        for (int im = 0; im < 4; im++)
            #pragma unroll
            for (int jn = 0; jn < 4; jn++){
                acc[im][jn] = __builtin_amdgcn_mfma_f32_16x16x32_bf16(
                    ah[im], bh[jn], acc[im][jn], 0, 0, 0);
                acc[im][jn] = __builtin_amdgcn_mfma_f32_16x16x32_bf16(
                    ah[im], bl[jn], acc[im][jn], 0, 0, 0);
                acc[im][jn] = __builtin_amdgcn_mfma_f32_16x16x32_bf16(
                    al[im], bh[jn], acc[im][jn], 0, 0, 0);
            }
    }

    #pragma unroll
    for (int im = 0; im < 4; im++){
        const int rb = m0 + wm + im*16 + lq*4;
        #pragma unroll
        for (int jn = 0; jn < 4; jn++){
            const int col = n0 + wn + jn*16 + l15;
            f32x4 a = acc[im][jn];
            #pragma unroll
            for (int r = 0; r < 4; r++){
                size_t idx = (size_t)(rb + r)*DM + col;
                out[idx] = a[r] * gws[idx];
            }
        }
    }
}

// ---------------------------------------------------------------------------
extern "C" void kernel_launch(void* const* d_in, const int* in_sizes, int n_in,
                              void* d_out, int out_size, void* d_ws, size_t ws_size,
                              hipStream_t stream)
{
    const float* x  = (const float*)d_in[0];
    const float* Wq = (const float*)d_in[1];
    const float* Wk = (const float*)d_in[2];
    const float* Wv = (const float*)d_in[3];
    const float* Wo = (const float*)d_in[4];
    const float* Wg = (const float*)d_in[5];
    float* out = (float*)d_out;

    float* w    = (float*)d_ws;
    float* qws  = w;                                   // 8192*256 f32
    float* kws  = qws + (size_t)MROWS*DIMQ;            // 8192*256 f32
    float* vws  = kws + (size_t)MROWS*DIMQ;            // 8192*256 f32
    float* gws  = vws + (size_t)MROWS*DIMQ;            // 8192*768 f32
    float* region = gws + (size_t)MROWS*DM;            // reused region (28.5 MB)
    unsigned short* xs = (unsigned short*)region;
    unsigned short* wt = xs + (size_t)MROWS*KSPLIT;
    float* Sws = region;
    float* Pws = Sws + (size_t)NBH*NCHUNK*STATE;
    unsigned short* attn_s = (unsigned short*)(Pws + (size_t)NBH*NCHUNK*STATE);
    unsigned short* wot = attn_s + (size_t)MROWS*KS2;
    // high-water: 78.8 MB (same as verified rounds 2-9)

    hipLaunchKernelGGL(prep, dim3(MROWS + 288), dim3(256), 0, stream,
                       x, Wq, Wk, Wv, Wg, xs, wt);
    hipLaunchKernelGGL(gemm_qkvg_mfma, dim3(64,12), dim3(256), 0, stream,
                       xs, wt, qws, kws, vws, gws);
    hipLaunchKernelGGL(chunk_state_wo, dim3(NBH*NCHUNK + 48), dim3(256), 0, stream,
                       kws, vws, Sws, Wo, wot);
    hipLaunchKernelGGL(prefix_scan, dim3((NBH*STATE + 255)/256), dim3(256), 0, stream,
                       Sws, Pws);
    hipLaunchKernelGGL(chunk_out_mfma, dim3(NBH*NCHUNK), dim3(256), 0, stream,
                       qws, kws, vws, Pws, attn_s);
    hipLaunchKernelGGL(gemm_out_mfma, dim3(64,6), dim3(256), 0, stream,
                       attn_s, wot, gws, out);
}